// Round 20
// baseline (486.181 us; speedup 1.0000x reference)
//
#include <hip/hip_runtime.h>
#include <cstdint>
#include <cstddef>

constexpr int B_ = 8;
constexpr int N_ = 2048;
constexpr int K_ = 10;

typedef __attribute__((ext_vector_type(8))) short bf16x8;
typedef __attribute__((ext_vector_type(4))) float f32x4;

__device__ __forceinline__ float lrelu(float v) { return fmaxf(v, 0.2f * v); }

__device__ __forceinline__ short f2bf(float f) {
    uint32_t u = __builtin_bit_cast(uint32_t, f);
    u += 0x7fff + ((u >> 16) & 1);  // RNE
    return (short)(u >> 16);
}
__device__ __forceinline__ float bf2f(short s) {
    uint32_t x = ((uint32_t)(unsigned short)s) << 16;
    return __builtin_bit_cast(float, x);
}

// ---------- transpose x (B,3,N) -> xt (B,N,3) ----------
__global__ void k_transpose(const float* __restrict__ x, float* __restrict__ xt) {
    int i = blockIdx.x * 256 + threadIdx.x;
    if (i >= B_ * N_) return;
    int b = i / N_, n = i % N_;
#pragma unroll
    for (int c = 0; c < 3; ++c)
        xt[(size_t)i * 3 + c] = x[((size_t)b * 3 + c) * N_ + n];
}

// ---------- weight preconvert: W4d, W5 plain bf16 ----------
__global__ void k_cvt(const float* __restrict__ W4, const float* __restrict__ W5,
                      short* __restrict__ Wb4, short* __restrict__ W5b) {
    int i = blockIdx.x * 256 + threadIdx.x;
    if (i < 256 * 128) {
        Wb4[i] = f2bf(W4[(size_t)(i >> 7) * 256 + (i & 127)]);
    } else {
        int k = i - 256 * 128;
        if (k < 512 * 512) W5b[k] = f2bf(W5[k]);
    }
}

// ---------- weight preconvert: W2d, W3d hi/lo bf16 ----------
__global__ void k_cvt2(const float* __restrict__ W2, const float* __restrict__ W3,
                       short* __restrict__ w2h, short* __restrict__ w2l,
                       short* __restrict__ w3h, short* __restrict__ w3l) {
    int i = blockIdx.x * 256 + threadIdx.x;
    if (i < 64 * 64) {
        float v = W2[(size_t)(i >> 6) * 128 + (i & 63)];
        short h = f2bf(v);
        w2h[i] = h; w2l[i] = f2bf(v - bf2f(h));
    } else if (i < 64 * 64 + 128 * 64) {
        int k = i - 64 * 64;
        float v = W3[(size_t)(k >> 6) * 128 + (k & 63)];
        short h = f2bf(v);
        w3h[k] = h; w3l[k] = f2bf(v - bf2f(h));
    }
}

// ---------- per-stage prep: hi/lo planes + row norms in one pass ----------
// Norm reduce replicates k_norms exactly (same element order, same shfl tree)
// -> bit-identical norms; hi/lo values identical to k_cvthl.
template <int C>
__global__ __launch_bounds__(256) void k_prep(const float* __restrict__ hcat, int OFF,
                                              unsigned short* __restrict__ xhi,
                                              unsigned short* __restrict__ xlo,
                                              float* __restrict__ nrm) {
    int gid = blockIdx.x * 256 + threadIdx.x;
    int wid = gid >> 6;
    int lane = threadIdx.x & 63;
    if (wid >= B_ * N_) return;
    const float* row = hcat + (size_t)wid * 512 + OFF;
    float v0 = row[lane];
    short h0 = f2bf(v0);
    xhi[(size_t)wid * C + lane] = (unsigned short)h0;
    xlo[(size_t)wid * C + lane] = (unsigned short)f2bf(v0 - bf2f(h0));
    float s = v0 * v0;
    if (C == 128) {
        float v1 = row[64 + lane];
        short h1 = f2bf(v1);
        xhi[(size_t)wid * C + 64 + lane] = (unsigned short)h1;
        xlo[(size_t)wid * C + 64 + lane] = (unsigned short)f2bf(v1 - bf2f(h1));
        s += v1 * v1;
    }
#pragma unroll
    for (int off = 32; off; off >>= 1) s += __shfl_down(s, off);
    if (lane == 0) nrm[wid] = s;
}

// ---------- block-1 kNN, column-split: chunk partial top-10 + merge ----------
// Same score formula as the proven k_knn3 (bit-identical values); chunk scan in
// ascending index with strict > ; k_kmerge finishes with value-desc/index-asc.
template <int CS>
__global__ __launch_bounds__(256) void k_knn3p(const float* __restrict__ x,  // (B,3,N)
                                               float* __restrict__ pv, int* __restrict__ pi) {
    constexpr int COLS = N_ / CS;      // 1024
    constexpr int NG = COLS / 64;      // 16
    __shared__ float xs[3][COLS];      // 12 KB
    __shared__ float ns[COLS];         // 4 KB
    const int b = blockIdx.x;
    const int w = threadIdx.x >> 6, lane = threadIdx.x & 63;
    const int n = blockIdx.y * 4 + w;
    const int cs = blockIdx.z;
    const int mbase = cs * COLS;
    for (int e = threadIdx.x; e < 3 * COLS; e += 256) {
        int c = e / COLS, mm = e % COLS;
        xs[c][mm] = x[((size_t)b * 3 + c) * N_ + mbase + mm];
    }
    __syncthreads();
    for (int m = threadIdx.x; m < COLS; m += 256) {
        float a0 = xs[0][m], a1 = xs[1][m], a2 = xs[2][m];
        ns[m] = a0 * a0 + a1 * a1 + a2 * a2;
    }
    __syncthreads();
    const float q0 = x[((size_t)b * 3 + 0) * N_ + n];
    const float q1 = x[((size_t)b * 3 + 1) * N_ + n];
    const float q2 = x[((size_t)b * 3 + 2) * N_ + n];

    float sv[NG];
#pragma unroll
    for (int g = 0; g < NG; ++g) {
        int m = g * 64 + lane;
        sv[g] = 2.f * (q0 * xs[0][m] + q1 * xs[1][m] + q2 * xs[2][m]) - ns[m];
    }
    float lm = sv[0];
#pragma unroll
    for (int g = 1; g < NG; ++g) lm = fmaxf(lm, sv[g]);
    float cur = lm, T = lm;
#pragma unroll
    for (int i = 0; i < K_; ++i) {
        float wm = cur;
#pragma unroll
        for (int off = 1; off < 64; off <<= 1) wm = fmaxf(wm, __shfl_xor(wm, off));
        T = wm;
        unsigned long long m = __ballot(cur == wm);
        int first = __ffsll(m) - 1;
        if (lane == first) cur = -INFINITY;
    }
    float kv[K_]; int ki[K_];
#pragma unroll
    for (int i = 0; i < K_; ++i) { kv[i] = -INFINITY; ki[i] = 0x7fffffff; }
#pragma unroll
    for (int g = 0; g < NG; ++g) {
        unsigned long long mk = __ballot(sv[g] >= T && sv[g] > kv[0]);
        while (mk) {
            int l = __ffsll(mk) - 1;
            mk &= mk - 1;
            float v = __shfl(sv[g], l);
            if (v > kv[0]) {
                kv[0] = v; ki[0] = mbase + g * 64 + l;
#pragma unroll
                for (int u = 0; u < K_ - 1; ++u)
                    if (kv[u] > kv[u + 1]) {
                        float tv = kv[u]; kv[u] = kv[u + 1]; kv[u + 1] = tv;
                        int tix = ki[u]; ki[u] = ki[u + 1]; ki[u + 1] = tix;
                    }
            }
        }
    }
    if (lane == 0) {
        float* opv = pv + (((size_t)b * N_ + n) * CS + cs) * K_;
        int*   opi = pi + (((size_t)b * N_ + n) * CS + cs) * K_;
#pragma unroll
        for (int k = 0; k < K_; ++k) { opv[k] = kv[K_ - 1 - k]; opi[k] = ki[K_ - 1 - k]; }
    }
}

// ---------- merge CS per-chunk desc top-10 lists (value desc, index asc) ----------
template <int CS>
__global__ __launch_bounds__(256) void k_kmerge(const float* __restrict__ pv,
                                                const int* __restrict__ pi,
                                                int* __restrict__ idxout) {
    int row = blockIdx.x * 256 + threadIdx.x;
    if (row >= B_ * N_) return;
    const float* rv = pv + (size_t)row * CS * K_;
    const int*   ri = pi + (size_t)row * CS * K_;
    int p[CS];
#pragma unroll
    for (int q = 0; q < CS; ++q) p[q] = 0;
    int* op = idxout + (size_t)row * K_;
    for (int k = 0; k < K_; ++k) {
        float bv = -INFINITY; int bi = 0x7fffffff, bq = 0;
#pragma unroll
        for (int q = 0; q < CS; ++q) {
            float v = rv[q * K_ + p[q]];
            int id = ri[q * K_ + p[q]];
            if (v > bv || (v == bv && id < bi)) { bv = v; bi = id; bq = q; }
        }
        op[k] = bi;
        ++p[bq];
    }
}

// ---------- scores GEMM via bf16 MFMA hi/lo 3-term, preconverted operands ----------
template <int C>
__global__ __launch_bounds__(256) void k_scores_mfma(const unsigned short* __restrict__ xhi,
                                                     const unsigned short* __restrict__ xlo,
                                                     const float* __restrict__ nrm,
                                                     float* __restrict__ S, int b0) {
    constexpr int RPC = C / 64;
    constexpr int NCH = 3 * RPC;
    constexpr int T = N_ / 64;
    __shared__ short AN[64 * 64];
    __shared__ short AM[64 * 64];
    const int bl = blockIdx.x;
    const int b = b0 + bl;
    int p = blockIdx.y;
    int r0 = 0, off = 0;
    while (off + (T - r0) <= p) { off += T - r0; ++r0; }
    const int ti = r0, tj = r0 + (p - off);
    const int n0 = ti * 64, m0 = tj * 64;
    const int t = threadIdx.x;
    const int lane = t & 63, w = t >> 6;
    const int colg = lane & 15, kg = lane >> 4;
    const size_t bbase = (size_t)b * N_;
    const float* nb = nrm + bbase;
    float* Sb = S + (size_t)bl * N_ * N_;

    f32x4 acc[4];
#pragma unroll
    for (int j = 0; j < 4; ++j) acc[j] = (f32x4){0.f, 0.f, 0.f, 0.f};

    for (int ch = 0; ch < NCH; ++ch) {
        const int region = ch / RPC;
        const int cc0 = (ch % RPC) * 64;
        const unsigned short* an_src = (region == 1) ? xlo : xhi;
        const unsigned short* am_src = (region == 2) ? xlo : xhi;
        __syncthreads();
#pragma unroll
        for (int e = 0; e < 2; ++e) {
            int idx = t + e * 256;
            int r = idx >> 3, k8 = idx & 7;
            uint4 vn = *(const uint4*)&an_src[(bbase + n0 + r) * C + cc0 + k8 * 8];
            uint4 vm = *(const uint4*)&am_src[(bbase + m0 + r) * C + cc0 + k8 * 8];
            int byte = (r * 128 + k8 * 16) ^ ((r & 7) << 4);
            *(uint4*)((char*)AN + byte) = vn;
            *(uint4*)((char*)AM + byte) = vm;
        }
        __syncthreads();
        const int arow = w * 16 + colg;
#pragma unroll
        for (int s = 0; s < 2; ++s) {
            int abyte = (arow * 128 + s * 64 + kg * 16) ^ ((arow & 7) << 4);
            bf16x8 af = *(const bf16x8*)((const char*)AN + abyte);
#pragma unroll
            for (int j = 0; j < 4; ++j) {
                int brow = j * 16 + colg;
                int bbyte = (brow * 128 + s * 64 + kg * 16) ^ ((brow & 7) << 4);
                bf16x8 bfr = *(const bf16x8*)((const char*)AM + bbyte);
                acc[j] = __builtin_amdgcn_mfma_f32_16x16x32_bf16(af, bfr, acc[j], 0, 0, 0);
            }
        }
    }
#pragma unroll
    for (int j = 0; j < 4; ++j) {
        float nm = nb[m0 + j * 16 + colg];
#pragma unroll
        for (int r = 0; r < 4; ++r) {
            int row = n0 + w * 16 + kg * 4 + r;
            Sb[(size_t)row * N_ + m0 + j * 16 + colg] = 2.f * acc[j][r] - nm;
        }
    }
    if (ti != tj) {
#pragma unroll
        for (int r = 0; r < 4; ++r) {
            int nrow = n0 + w * 16 + kg * 4 + r;
            float nn = nb[nrow];
#pragma unroll
            for (int j = 0; j < 4; ++j)
                Sb[(size_t)(m0 + j * 16 + colg) * N_ + nrow] = 2.f * acc[j][r] - nn;
        }
    }
}

// ---------- top-K scan: threshold-primed ballot-pop ----------
__global__ __launch_bounds__(256) void k_topk(const float* __restrict__ S,
                                              int* __restrict__ idxout, int b0) {
    const int bl = blockIdx.x, b = b0 + bl;
    const int wv = threadIdx.x >> 6, lane = threadIdx.x & 63;
    const int n = blockIdx.y * 4 + wv;
    const float* row = S + (size_t)bl * N_ * N_ + (size_t)n * N_;

    float sv[32];
#pragma unroll
    for (int g = 0; g < 32; ++g) sv[g] = __builtin_nontemporal_load(&row[g * 64 + lane]);

    float lm = sv[0];
#pragma unroll
    for (int g = 1; g < 32; ++g) lm = fmaxf(lm, sv[g]);

    float cur = lm, T = lm;
#pragma unroll
    for (int i = 0; i < K_; ++i) {
        float wm = cur;
#pragma unroll
        for (int off = 1; off < 64; off <<= 1) wm = fmaxf(wm, __shfl_xor(wm, off));
        T = wm;
        unsigned long long m = __ballot(cur == wm);
        int first = __ffsll(m) - 1;
        if (lane == first) cur = -INFINITY;
    }

    float kv[K_]; int ki[K_];
#pragma unroll
    for (int i = 0; i < K_; ++i) { kv[i] = -INFINITY; ki[i] = 0x7fffffff; }

#pragma unroll
    for (int g = 0; g < 32; ++g) {
        unsigned long long mk = __ballot(sv[g] >= T && sv[g] > kv[0]);
        while (mk) {
            int l = __ffsll(mk) - 1;
            mk &= mk - 1;
            float v = __shfl(sv[g], l);
            if (v > kv[0]) {
                kv[0] = v; ki[0] = g * 64 + l;
#pragma unroll
                for (int u = 0; u < K_ - 1; ++u)
                    if (kv[u] > kv[u + 1]) {
                        float tv = kv[u]; kv[u] = kv[u + 1]; kv[u + 1] = tv;
                        int tix = ki[u]; ki[u] = ki[u + 1]; ki[u + 1] = tix;
                    }
            }
        }
    }
    if (lane == 0) {
        int* op = idxout + ((size_t)b * N_ + n) * K_;
#pragma unroll
        for (int k = 0; k < K_; ++k) op[k] = ki[K_ - 1 - k];
    }
}

// ---------- center term ----------
template <int C, int O>
__global__ __launch_bounds__(256) void k_center(const float* __restrict__ xt, int LD, int OFF,
                                                const float* __restrict__ W,
                                                float* __restrict__ tbuf) {
    constexpr int KC = (C == 3) ? 4 : 32;
    __shared__ __align__(16) float XT[64][36];
    __shared__ __align__(16) float WDT[KC][68];
    const int b = blockIdx.x;
    const int n0 = blockIdx.y * 64;
    const int ob = blockIdx.z * 64;
    const int t = threadIdx.x;
    const int tn = t & 15, to = t >> 4;
    const float* xb = xt + ((size_t)b * N_) * LD + OFF;
    float4 acc[4];
#pragma unroll
    for (int i = 0; i < 4; ++i) acc[i] = make_float4(0, 0, 0, 0);
    for (int c0 = 0; c0 < C; c0 += KC) {
        __syncthreads();
        for (int e = t; e < 64 * KC; e += 256) {
            int r = e / KC, cc = e % KC;
            XT[r][cc] = (C == 3) ? ((cc < 3) ? xb[(size_t)(n0 + r) * LD + cc] : 0.f)
                                 : xb[(size_t)(n0 + r) * LD + c0 + cc];
        }
        for (int e = t; e < 64 * KC; e += 256) {
            int oo = e / KC, cc = e % KC;
            float wd, wc;
            if (C == 3) {
                wd = (cc < 3) ? W[(ob + oo) * 6 + cc] : 0.f;
                wc = (cc < 3) ? W[(ob + oo) * 6 + 3 + cc] : 0.f;
            } else {
                wd = W[(size_t)(ob + oo) * (2 * C) + c0 + cc];
                wc = W[(size_t)(ob + oo) * (2 * C) + C + c0 + cc];
            }
            WDT[cc][oo] = wc - wd;
        }
        __syncthreads();
#pragma unroll 4
        for (int cc = 0; cc < KC; ++cc) {
            float4 w4 = *(const float4*)&WDT[cc][to * 4];
#pragma unroll
            for (int i = 0; i < 4; ++i) {
                float a = XT[tn * 4 + i][cc];
                acc[i].x += a * w4.x; acc[i].y += a * w4.y;
                acc[i].z += a * w4.z; acc[i].w += a * w4.w;
            }
        }
    }
#pragma unroll
    for (int i = 0; i < 4; ++i)
        *(float4*)&tbuf[((size_t)b * N_ + n0 + tn * 4 + i) * O + ob + to * 4] = acc[i];
}

// ---------- fp32 edge conv (block 1 only, C=3) ----------
template <int C, int O>
__global__ __launch_bounds__(256) void k_conv(const float* __restrict__ xt, int LDI, int OFFI,
                                              const int* __restrict__ idx,
                                              const float* __restrict__ W,
                                              const float* __restrict__ tbuf,
                                              float* __restrict__ hout, int OFFO) {
    constexpr int KC = (C == 3) ? 4 : 32;
    __shared__ __align__(16) float A[160][36];
    __shared__ __align__(16) float WT[KC][68];
    __shared__ int nb_s[160];
    const int b = blockIdx.x;
    const int n0 = blockIdx.y * 16;
    const int t = threadIdx.x;
    const int p = t >> 4, og = t & 15;
    if (t < 160) nb_s[t] = idx[((size_t)b * N_ + n0 + t / K_) * K_ + (t % K_)];
    const float* xb = xt + ((size_t)b * N_) * LDI + OFFI;

    for (int ob = 0; ob < O; ob += 64) {
        float4 acc[K_];
#pragma unroll
        for (int j = 0; j < K_; ++j) acc[j] = make_float4(0, 0, 0, 0);
        for (int c0 = 0; c0 < C; c0 += KC) {
            __syncthreads();
            if (C == 3) {
                for (int e = t; e < 160 * 4; e += 256) {
                    int r = e / 4, cc = e % 4;
                    A[r][cc] = (cc < 3) ? xb[(size_t)nb_s[r] * LDI + cc] : 0.f;
                }
            } else {
                for (int e = t; e < 160 * 8; e += 256) {
                    int r = e / 8, c4 = e % 8;
                    *(float4*)&A[r][c4 * 4] =
                        *(const float4*)&xb[(size_t)nb_s[r] * LDI + c0 + c4 * 4];
                }
            }
            for (int e = t; e < 64 * KC; e += 256) {
                int oo = e / KC, cc = e % KC;
                float w;
                if (C == 3) w = (cc < 3) ? W[(ob + oo) * 6 + cc] : 0.f;
                else        w = W[(size_t)(ob + oo) * (2 * C) + c0 + cc];
                WT[cc][oo] = w;
            }
            __syncthreads();
#pragma unroll 4
            for (int cc = 0; cc < KC; ++cc) {
                float4 w4 = *(const float4*)&WT[cc][og * 4];
#pragma unroll
                for (int j = 0; j < K_; ++j) {
                    float a = A[p * K_ + j][cc];
                    acc[j].x += a * w4.x; acc[j].y += a * w4.y;
                    acc[j].z += a * w4.z; acc[j].w += a * w4.w;
                }
            }
        }
        float4 tv = *(const float4*)&tbuf[((size_t)b * N_ + n0 + p) * O + ob + og * 4];
        float4 mx = acc[0];
#pragma unroll
        for (int j = 1; j < K_; ++j) {
            mx.x = fmaxf(mx.x, acc[j].x); mx.y = fmaxf(mx.y, acc[j].y);
            mx.z = fmaxf(mx.z, acc[j].z); mx.w = fmaxf(mx.w, acc[j].w);
        }
        float4 r;
        r.x = lrelu(mx.x + tv.x); r.y = lrelu(mx.y + tv.y);
        r.z = lrelu(mx.z + tv.z); r.w = lrelu(mx.w + tv.w);
        *(float4*)&hout[((size_t)b * N_ + n0 + p) * 512 + OFFO + ob + og * 4] = r;
    }
}

// ---------- blocks 2-3 edge conv via hi/lo MFMA ----------
template <int O>
__global__ __launch_bounds__(256) void k_conv23_mfma(const float* __restrict__ hcat, int OFFI,
                                                     const int* __restrict__ idx,
                                                     const short* __restrict__ Wh,
                                                     const short* __restrict__ Wl,
                                                     const float* __restrict__ tbuf,
                                                     float* __restrict__ hout, int OFFO) {
    constexpr int CT = O / 64;
    __shared__ short Ah[160 * 64];
    __shared__ short Al[160 * 64];
    __shared__ int nb_s[160];
    const int b = blockIdx.x;
    const int n0 = blockIdx.y * 16;
    const int t = threadIdx.x;
    const int lane = t & 63, wv = t >> 6;
    const int colg = lane & 15, kg = lane >> 4;
    if (t < 160) nb_s[t] = idx[((size_t)b * N_ + n0 + t / K_) * K_ + (t % K_)];
    __syncthreads();
    for (int e = t; e < 160 * 16; e += 256) {
        int r = e >> 4, q = e & 15;
        const float4 v = *(const float4*)&hcat[((size_t)b * N_ + nb_s[r]) * 512 + OFFI + q * 4];
        float a4[4] = {v.x, v.y, v.z, v.w};
        short sh[4], sl[4];
#pragma unroll
        for (int c2 = 0; c2 < 4; ++c2) {
            sh[c2] = f2bf(a4[c2]);
            sl[c2] = f2bf(a4[c2] - bf2f(sh[c2]));
        }
        int byte = r * 128 + ((q * 8) ^ (((r / K_) & 7) << 4));
        *(short4*)((char*)Ah + byte) = make_short4(sh[0], sh[1], sh[2], sh[3]);
        *(short4*)((char*)Al + byte) = make_short4(sl[0], sl[1], sl[2], sl[3]);
    }
    bf16x8 bh[CT][2], blo[CT][2];
    const int obase = wv * (O / 4);
#pragma unroll
    for (int ct = 0; ct < CT; ++ct)
#pragma unroll
        for (int ks = 0; ks < 2; ++ks) {
            int o = obase + ct * 16 + colg;
            bh[ct][ks]  = *(const bf16x8*)&Wh[(size_t)o * 64 + ks * 32 + kg * 8];
            blo[ct][ks] = *(const bf16x8*)&Wl[(size_t)o * 64 + ks * 32 + kg * 8];
        }
    __syncthreads();

    f32x4 macc[CT];
#pragma unroll
    for (int ct = 0; ct < CT; ++ct)
        macc[ct] = (f32x4){-INFINITY, -INFINITY, -INFINITY, -INFINITY};

    const int aswz = (colg & 7) << 4;
#pragma unroll
    for (int j = 0; j < K_; ++j) {
        const int arow = colg * K_ + j;
        bf16x8 afh[2], afl[2];
#pragma unroll
        for (int ks = 0; ks < 2; ++ks) {
            int byte = arow * 128 + ((ks * 64 + kg * 16) ^ aswz);
            afh[ks] = *(const bf16x8*)((const char*)Ah + byte);
            afl[ks] = *(const bf16x8*)((const char*)Al + byte);
        }
        f32x4 acc[CT];
#pragma unroll
        for (int ct = 0; ct < CT; ++ct) acc[ct] = (f32x4){0.f, 0.f, 0.f, 0.f};
#pragma unroll
        for (int ks = 0; ks < 2; ++ks)
#pragma unroll
            for (int ct = 0; ct < CT; ++ct)
                acc[ct] = __builtin_amdgcn_mfma_f32_16x16x32_bf16(afh[ks], bh[ct][ks], acc[ct], 0, 0, 0);
#pragma unroll
        for (int ks = 0; ks < 2; ++ks)
#pragma unroll
            for (int ct = 0; ct < CT; ++ct)
                acc[ct] = __builtin_amdgcn_mfma_f32_16x16x32_bf16(afl[ks], bh[ct][ks], acc[ct], 0, 0, 0);
#pragma unroll
        for (int ks = 0; ks < 2; ++ks)
#pragma unroll
            for (int ct = 0; ct < CT; ++ct)
                acc[ct] = __builtin_amdgcn_mfma_f32_16x16x32_bf16(afh[ks], blo[ct][ks], acc[ct], 0, 0, 0);
#pragma unroll
        for (int ct = 0; ct < CT; ++ct) {
            macc[ct].x = fmaxf(macc[ct].x, acc[ct].x);
            macc[ct].y = fmaxf(macc[ct].y, acc[ct].y);
            macc[ct].z = fmaxf(macc[ct].z, acc[ct].z);
            macc[ct].w = fmaxf(macc[ct].w, acc[ct].w);
        }
    }
#pragma unroll
    for (int ct = 0; ct < CT; ++ct)
#pragma unroll
        for (int r = 0; r < 4; ++r) {
            int p = kg * 4 + r;
            int o = obase + ct * 16 + colg;
            float v = macc[ct][r] + tbuf[((size_t)b * N_ + n0 + p) * O + o];
            hout[((size_t)b * N_ + n0 + p) * 512 + OFFO + o] = lrelu(v);
        }
}

// ---------- block-4 edge conv via bf16 MFMA ----------
__global__ __launch_bounds__(256) void k_conv4_mfma(const float* __restrict__ hcat,
                                                    const int* __restrict__ idx,
                                                    const short* __restrict__ Wb,
                                                    const float* __restrict__ tbuf,
                                                    float* __restrict__ hout) {
    __shared__ short Ab[160 * 128];
    __shared__ int nb_s[160];
    const int b = blockIdx.x;
    const int n0 = blockIdx.y * 16;
    const int t = threadIdx.x;
    const int lane = t & 63, wv = t >> 6;
    const int colg = lane & 15, kg = lane >> 4;
    if (t < 160) nb_s[t] = idx[((size_t)b * N_ + n0 + t / K_) * K_ + (t % K_)];
    __syncthreads();
    for (int e = t; e < 160 * 32; e += 256) {
        int r = e >> 5, q = e & 31;
        const float4 v = *(const float4*)&hcat[((size_t)b * N_ + nb_s[r]) * 512 + 128 + q * 4];
        short4 s4 = { f2bf(v.x), f2bf(v.y), f2bf(v.z), f2bf(v.w) };
        int byte = r * 256 + ((q * 8) ^ (((r / K_) & 7) << 4));
        *(short4*)((char*)Ab + byte) = s4;
    }
    bf16x8 bf[4][4];
    const int ob = wv * 64;
#pragma unroll
    for (int nt = 0; nt < 4; ++nt)
#pragma unroll
        for (int ks = 0; ks < 4; ++ks)
            bf[nt][ks] = *(const bf16x8*)&Wb[(size_t)(ob + nt * 16 + colg) * 128 + ks * 32 + kg * 8];
    __syncthreads();

    f32x4 macc[4];
#pragma unroll
    for (int nt = 0; nt < 4; ++nt)
        macc[nt] = (f32x4){-INFINITY, -INFINITY, -INFINITY, -INFINITY};

    const int arow = colg * K_;
    const int aswz = (colg & 7) << 4;
#pragma unroll
    for (int j = 0; j < K_; ++j) {
        f32x4 acc[4];
#pragma unroll
        for (int nt = 0; nt < 4; ++nt) acc[nt] = (f32x4){0.f, 0.f, 0.f, 0.f};
#pragma unroll
        for (int ks = 0; ks < 4; ++ks) {
            int byte = (arow + j) * 256 + (((ks * 32 + kg * 8) * 2) ^ aswz);
            bf16x8 af = *(const bf16x8*)((const char*)Ab + byte);
#pragma unroll
            for (int nt = 0; nt < 4; ++nt)
                acc[nt] = __builtin_amdgcn_mfma_f32_16x16x32_bf16(af, bf[nt][ks], acc[nt], 0, 0, 0);
        }
#pragma unroll
        for (int nt = 0; nt < 4; ++nt) {
            macc[nt].x = fmaxf(macc[nt].x, acc[nt].x);
            macc[nt].y = fmaxf(macc[nt].y, acc[nt].y);
            macc[nt].z = fmaxf(macc[nt].z, acc[nt].z);
            macc[nt].w = fmaxf(macc[nt].w, acc[nt].w);
        }
    }
#pragma unroll
    for (int nt = 0; nt < 4; ++nt)
#pragma unroll
        for (int r = 0; r < 4; ++r) {
            int p = kg * 4 + r;
            int o = ob + nt * 16 + colg;
            float v = macc[nt][r] + tbuf[((size_t)b * N_ + n0 + p) * 256 + o];
            hout[((size_t)b * N_ + n0 + p) * 512 + 256 + o] = lrelu(v);
        }
}

// ---------- final conv W5 via bf16 MFMA + fused lrelu/max/sum reduce ----------
__global__ __launch_bounds__(256) void k_final_mfma(const float* __restrict__ hcat,
                                                    const short* __restrict__ W5b,
                                                    float* __restrict__ pmax,
                                                    float* __restrict__ psum) {
    __shared__ short Ab[64 * 128];
    const int b = blockIdx.x, nc = blockIdx.y, obk = blockIdx.z;
    const int n0 = nc * 64, ob = obk * 64;
    const int t = threadIdx.x, lane = t & 63, wv = t >> 6;
    const int colg = lane & 15, kg = lane >> 4;
    const int o = ob + wv * 16 + colg;

    f32x4 acc[4];
#pragma unroll
    for (int mt = 0; mt < 4; ++mt) acc[mt] = (f32x4){0.f, 0.f, 0.f, 0.f};

    for (int kc = 0; kc < 4; ++kc) {
        __syncthreads();
        for (int e = t; e < 64 * 32; e += 256) {
            int r = e >> 5, q = e & 31;
            const float4 v = *(const float4*)&hcat[((size_t)b * N_ + n0 + r) * 512 + kc * 128 + q * 4];
            short4 s4 = { f2bf(v.x), f2bf(v.y), f2bf(v.z), f2bf(v.w) };
            int byte = r * 256 + ((q * 8) ^ ((r & 7) << 4));
            *(short4*)((char*)Ab + byte) = s4;
        }
        __syncthreads();
#pragma unroll
        for (int ks = 0; ks < 4; ++ks) {
            bf16x8 bfrag = *(const bf16x8*)&W5b[(size_t)o * 512 + kc * 128 + ks * 32 + kg * 8];
#pragma unroll
            for (int mt = 0; mt < 4; ++mt) {
                int row = mt * 16 + colg;
                int byte = row * 256 + (((ks * 32 + kg * 8) * 2) ^ ((row & 7) << 4));
                bf16x8 af = *(const bf16x8*)((const char*)Ab + byte);
                acc[mt] = __builtin_amdgcn_mfma_f32_16x16x32_bf16(af, bfrag, acc[mt], 0, 0, 0);
            }
        }
    }
    float mx = -INFINITY, sm = 0.f;
#pragma unroll
    for (int mt = 0; mt < 4; ++mt)
#pragma unroll
        for (int r = 0; r < 4; ++r) {
            float v = lrelu(acc[mt][r]);
            mx = fmaxf(mx, v); sm += v;
        }
    mx = fmaxf(mx, __shfl_xor(mx, 16)); sm += __shfl_xor(sm, 16);
    mx = fmaxf(mx, __shfl_xor(mx, 32)); sm += __shfl_xor(sm, 32);
    if (lane < 16) {
        pmax[((size_t)b * 512 + ob + wv * 16 + lane) * 32 + nc] = mx;
        psum[((size_t)b * 512 + ob + wv * 16 + lane) * 32 + nc] = sm;
    }
}

// ---------- pool combine ----------
__global__ __launch_bounds__(256) void k_pool(const float* __restrict__ pmax,
                                              const float* __restrict__ psum,
                                              float* __restrict__ f) {
    int i = blockIdx.x * 256 + threadIdx.x;
    if (i >= B_ * 512) return;
    int b = i >> 9, o = i & 511;
    const float* pm = pmax + (size_t)i * 32;
    const float* ps = psum + (size_t)i * 32;
    float mm = -INFINITY, ss = 0.f;
#pragma unroll
    for (int q = 0; q < 32; ++q) { mm = fmaxf(mm, pm[q]); ss += ps[q]; }
    f[(size_t)b * 1024 + o] = mm;
    f[(size_t)b * 1024 + 512 + o] = ss * (1.0f / 2048.0f);
}

// ---------- FC1 ----------
__global__ __launch_bounds__(256) void k_fc1(const float* __restrict__ f,
                                             const float* __restrict__ L1,
                                             float* __restrict__ f1) {
    __shared__ float fs[8][1024];
    const int t = threadIdx.x, lane = t & 63, w = t >> 6;
    for (int e = t; e < 2048; e += 256)
        *(float4*)&fs[0][e * 4] = *(const float4*)&f[e * 4];
    __syncthreads();
    const int o = blockIdx.x * 4 + w;
    float acc[8];
#pragma unroll
    for (int b = 0; b < 8; ++b) acc[b] = 0.f;
    const float* Lrow = L1 + (size_t)o * 1024;
#pragma unroll
    for (int e = 0; e < 16; ++e) {
        float wv = Lrow[e * 64 + lane];
#pragma unroll
        for (int b = 0; b < 8; ++b) acc[b] += wv * fs[b][e * 64 + lane];
    }
#pragma unroll
    for (int off = 32; off; off >>= 1)
#pragma unroll
        for (int b = 0; b < 8; ++b) acc[b] += __shfl_xor(acc[b], off);
#pragma unroll
    for (int b = 0; b < 8; ++b)
        if (lane == b) f1[(size_t)b * 512 + o] = lrelu(acc[b]);
}

// ---------- FC2 ----------
__global__ __launch_bounds__(256) void k_fc2(const float* __restrict__ f1,
                                             const float* __restrict__ L2,
                                             const float* __restrict__ b2,
                                             float* __restrict__ out) {
    __shared__ float fs[8][512];
    const int t = threadIdx.x, lane = t & 63, w = t >> 6;
    for (int e = t; e < 1024; e += 256)
        *(float4*)&fs[0][e * 4] = *(const float4*)&f1[e * 4];
    __syncthreads();
    const int o = blockIdx.x * 4 + w;
    float acc[8];
#pragma unroll
    for (int b = 0; b < 8; ++b) acc[b] = 0.f;
    const float* Lrow = L2 + (size_t)o * 512;
#pragma unroll
    for (int e = 0; e < 8; ++e) {
        float wv = Lrow[e * 64 + lane];
#pragma unroll
        for (int b = 0; b < 8; ++b) acc[b] += wv * fs[b][e * 64 + lane];
    }
#pragma unroll
    for (int off = 32; off; off >>= 1)
#pragma unroll
        for (int b = 0; b < 8; ++b) acc[b] += __shfl_xor(acc[b], off);
    float bb = b2[o];
#pragma unroll
    for (int b = 0; b < 8; ++b)
        if (lane == b) out[(size_t)b * 256 + o] = lrelu(acc[b] + bb);
}

extern "C" void kernel_launch(void* const* d_in, const int* in_sizes, int n_in,
                              void* d_out, int out_size, void* d_ws, size_t ws_size,
                              hipStream_t stream) {
    (void)in_sizes; (void)n_in; (void)out_size;
    const float* x  = (const float*)d_in[0];
    const float* W1 = (const float*)d_in[1];
    const float* W2 = (const float*)d_in[2];
    const float* W3 = (const float*)d_in[3];
    const float* W4 = (const float*)d_in[4];
    const float* W5 = (const float*)d_in[5];
    const float* L1 = (const float*)d_in[6];
    const float* L2 = (const float*)d_in[7];
    const float* b2 = (const float*)d_in[8];
    float* out = (float*)d_out;

    constexpr int CS = 2;

    // workspace layout (float units)
    float* ws   = (float*)d_ws;
    float* xt   = ws;                                    // 49152
    float* nrm  = xt + (size_t)B_ * N_ * 3;              // 16384
    int*   idxb = (int*)(nrm + (size_t)B_ * N_);         // 163840
    float* tb   = (float*)(idxb + (size_t)B_ * N_ * K_); // 4194304
    float* hcat = tb + (size_t)B_ * N_ * 256;            // 8388608
    float* pmax = hcat + (size_t)B_ * N_ * 512;          // 131072
    float* psum = pmax + (size_t)B_ * 512 * 32;          // 131072
    short* wb4  = (short*)(psum + (size_t)B_ * 512 * 32);// 16384 floats
    short* w5b  = wb4 + 256 * 128;                       // 131072 floats
    short* w2h  = w5b + 512 * 512;                       // 64*64
    short* w2l  = w2h + 64 * 64;
    short* w3h  = w2l + 64 * 64;                         // 128*64
    short* w3l  = w3h + 128 * 64;
    float* fbuf = (float*)(w3l + 128 * 64);              // 8192
    float* f1b  = fbuf + 8192;                           // 4096
    unsigned short* xh = (unsigned short*)(f1b + 4096);  // B*N*128 shorts
    unsigned short* xl = xh + (size_t)B_ * N_ * 128;
    float* pv   = (float*)(xl + (size_t)B_ * N_ * 128);  // B*N*CS*K = 327680
    int*   pi   = (int*)(pv + (size_t)B_ * N_ * CS * K_);// 327680
    float* scor = (float*)(pi + (size_t)B_ * N_ * CS * K_);

    const size_t base_f = 49152 + 16384 + 163840 + 4194304 + 8388608 +
                          131072 + 131072 + 16384 + 131072 + 12288 + 8192 + 4096 +
                          2097152 + 655360;
    const size_t nsq = (size_t)N_ * N_;
    size_t avail = (ws_size / 4 > base_f) ? (ws_size / 4 - base_f) : 0;
    int CH = 1;
    if (avail >= 8 * nsq) CH = 8;
    else if (avail >= 4 * nsq) CH = 4;
    else if (avail >= 2 * nsq) CH = 2;

    constexpr int TP = (N_ / 64) * (N_ / 64 + 1) / 2;  // 528

    dim3 blk(256);
    k_transpose<<<dim3((B_ * N_ + 255) / 256), blk, 0, stream>>>(x, xt);
    k_cvt<<<dim3((256 * 128 + 512 * 512 + 255) / 256), blk, 0, stream>>>(W4, W5, wb4, w5b);
    k_cvt2<<<dim3((64 * 64 + 128 * 64 + 255) / 256), blk, 0, stream>>>(W2, W3, w2h, w2l, w3h, w3l);

    // block 1: column-split fused kNN + merge
    k_knn3p<CS><<<dim3(B_, N_ / 4, CS), blk, 0, stream>>>(x, pv, pi);
    k_kmerge<CS><<<dim3(B_ * N_ / 256), blk, 0, stream>>>(pv, pi, idxb);
    k_center<3, 64><<<dim3(B_, N_ / 64, 1), blk, 0, stream>>>(xt, 3, 0, W1, tb);
    k_conv<3, 64><<<dim3(B_, N_ / 16), blk, 0, stream>>>(xt, 3, 0, idxb, W1, tb, hcat, 0);

    // block 2
    k_prep<64><<<dim3(B_ * N_ / 4), blk, 0, stream>>>(hcat, 0, xh, xl, nrm);
    for (int b0 = 0; b0 < B_; b0 += CH) {
        k_scores_mfma<64><<<dim3(CH, TP), blk, 0, stream>>>(xh, xl, nrm, scor, b0);
        k_topk<<<dim3(CH, N_ / 4), blk, 0, stream>>>(scor, idxb, b0);
    }
    k_center<64, 64><<<dim3(B_, N_ / 64, 1), blk, 0, stream>>>(hcat, 512, 0, W2, tb);
    k_conv23_mfma<64><<<dim3(B_, N_ / 16), blk, 0, stream>>>(hcat, 0, idxb, w2h, w2l, tb, hcat, 64);

    // block 3
    k_prep<64><<<dim3(B_ * N_ / 4), blk, 0, stream>>>(hcat, 64, xh, xl, nrm);
    for (int b0 = 0; b0 < B_; b0 += CH) {
        k_scores_mfma<64><<<dim3(CH, TP), blk, 0, stream>>>(xh, xl, nrm, scor, b0);
        k_topk<<<dim3(CH, N_ / 4), blk, 0, stream>>>(scor, idxb, b0);
    }
    k_center<64, 128><<<dim3(B_, N_ / 64, 2), blk, 0, stream>>>(hcat, 512, 64, W3, tb);
    k_conv23_mfma<128><<<dim3(B_, N_ / 16), blk, 0, stream>>>(hcat, 64, idxb, w3h, w3l, tb, hcat, 128);

    // block 4 (MFMA conv)
    k_prep<128><<<dim3(B_ * N_ / 4), blk, 0, stream>>>(hcat, 128, xh, xl, nrm);
    for (int b0 = 0; b0 < B_; b0 += CH) {
        k_scores_mfma<128><<<dim3(CH, TP), blk, 0, stream>>>(xh, xl, nrm, scor, b0);
        k_topk<<<dim3(CH, N_ / 4), blk, 0, stream>>>(scor, idxb, b0);
    }
    k_center<128, 256><<<dim3(B_, N_ / 64, 4), blk, 0, stream>>>(hcat, 512, 128, W4, tb);
    k_conv4_mfma<<<dim3(B_, N_ / 16), blk, 0, stream>>>(hcat, idxb, wb4, tb, hcat);

    // final conv + parallelized head
    k_final_mfma<<<dim3(B_, 32, 8), blk, 0, stream>>>(hcat, w5b, pmax, psum);
    k_pool<<<dim3(B_ * 512 / 256), blk, 0, stream>>>(pmax, psum, fbuf);
    k_fc1<<<dim3(128), blk, 0, stream>>>(fbuf, L1, f1b);
    k_fc2<<<dim3(64), blk, 0, stream>>>(f1b, L2, b2, out);
}

// Round 21
// 459.017 us; speedup vs baseline: 1.0592x; 1.0592x over previous
//
#include <hip/hip_runtime.h>
#include <cstdint>
#include <cstddef>

constexpr int B_ = 8;
constexpr int N_ = 2048;
constexpr int K_ = 10;

typedef __attribute__((ext_vector_type(8))) short bf16x8;
typedef __attribute__((ext_vector_type(4))) float f32x4;

__device__ __forceinline__ float lrelu(float v) { return fmaxf(v, 0.2f * v); }

__device__ __forceinline__ short f2bf(float f) {
    uint32_t u = __builtin_bit_cast(uint32_t, f);
    u += 0x7fff + ((u >> 16) & 1);  // RNE
    return (short)(u >> 16);
}
__device__ __forceinline__ float bf2f(short s) {
    uint32_t x = ((uint32_t)(unsigned short)s) << 16;
    return __builtin_bit_cast(float, x);
}

// ---------- transpose x (B,3,N) -> xt (B,N,3) ----------
__global__ void k_transpose(const float* __restrict__ x, float* __restrict__ xt) {
    int i = blockIdx.x * 256 + threadIdx.x;
    if (i >= B_ * N_) return;
    int b = i / N_, n = i % N_;
#pragma unroll
    for (int c = 0; c < 3; ++c)
        xt[(size_t)i * 3 + c] = x[((size_t)b * 3 + c) * N_ + n];
}

// ---------- weight preconvert: W4d, W5 plain bf16 ----------
__global__ void k_cvt(const float* __restrict__ W4, const float* __restrict__ W5,
                      short* __restrict__ Wb4, short* __restrict__ W5b) {
    int i = blockIdx.x * 256 + threadIdx.x;
    if (i < 256 * 128) {
        Wb4[i] = f2bf(W4[(size_t)(i >> 7) * 256 + (i & 127)]);
    } else {
        int k = i - 256 * 128;
        if (k < 512 * 512) W5b[k] = f2bf(W5[k]);
    }
}

// ---------- weight preconvert: W2d, W3d hi/lo bf16 ----------
__global__ void k_cvt2(const float* __restrict__ W2, const float* __restrict__ W3,
                       short* __restrict__ w2h, short* __restrict__ w2l,
                       short* __restrict__ w3h, short* __restrict__ w3l) {
    int i = blockIdx.x * 256 + threadIdx.x;
    if (i < 64 * 64) {
        float v = W2[(size_t)(i >> 6) * 128 + (i & 63)];
        short h = f2bf(v);
        w2h[i] = h; w2l[i] = f2bf(v - bf2f(h));
    } else if (i < 64 * 64 + 128 * 64) {
        int k = i - 64 * 64;
        float v = W3[(size_t)(k >> 6) * 128 + (k & 63)];
        short h = f2bf(v);
        w3h[k] = h; w3l[k] = f2bf(v - bf2f(h));
    }
}

// ---------- per-stage prep: hi/lo planes + row norms in one pass ----------
// Norm reduce replicates k_norms exactly (same element order, same shfl tree).
template <int C>
__global__ __launch_bounds__(256) void k_prep(const float* __restrict__ hcat, int OFF,
                                              unsigned short* __restrict__ xhi,
                                              unsigned short* __restrict__ xlo,
                                              float* __restrict__ nrm) {
    int gid = blockIdx.x * 256 + threadIdx.x;
    int wid = gid >> 6;
    int lane = threadIdx.x & 63;
    if (wid >= B_ * N_) return;
    const float* row = hcat + (size_t)wid * 512 + OFF;
    float v0 = row[lane];
    short h0 = f2bf(v0);
    xhi[(size_t)wid * C + lane] = (unsigned short)h0;
    xlo[(size_t)wid * C + lane] = (unsigned short)f2bf(v0 - bf2f(h0));
    float s = v0 * v0;
    if (C == 128) {
        float v1 = row[64 + lane];
        short h1 = f2bf(v1);
        xhi[(size_t)wid * C + 64 + lane] = (unsigned short)h1;
        xlo[(size_t)wid * C + 64 + lane] = (unsigned short)f2bf(v1 - bf2f(h1));
        s += v1 * v1;
    }
#pragma unroll
    for (int off = 32; off; off >>= 1) s += __shfl_down(s, off);
    if (lane == 0) nrm[wid] = s;
}

// ---------- fused block-1 kNN (C=3): whole point set in LDS, topk in-register ----------
__global__ __launch_bounds__(256) void k_knn3(const float* __restrict__ x,
                                              int* __restrict__ idxout) {
    __shared__ float xs[3][N_];
    __shared__ float ns[N_];
    const int b = blockIdx.x;
    const int w = threadIdx.x >> 6, lane = threadIdx.x & 63;
    const int n = blockIdx.y * 4 + w;
    for (int e = threadIdx.x; e < 3 * N_; e += 256)
        xs[e / N_][e % N_] = x[(size_t)b * 3 * N_ + e];
    __syncthreads();
    for (int m = threadIdx.x; m < N_; m += 256) {
        float a0 = xs[0][m], a1 = xs[1][m], a2 = xs[2][m];
        ns[m] = a0 * a0 + a1 * a1 + a2 * a2;
    }
    __syncthreads();
    const float q0 = xs[0][n], q1 = xs[1][n], q2 = xs[2][n];

    float sv[32];
#pragma unroll
    for (int g = 0; g < 32; ++g) {
        int m = g * 64 + lane;
        sv[g] = 2.f * (q0 * xs[0][m] + q1 * xs[1][m] + q2 * xs[2][m]) - ns[m];
    }
    float lm = sv[0];
#pragma unroll
    for (int g = 1; g < 32; ++g) lm = fmaxf(lm, sv[g]);
    float cur = lm, T = lm;
#pragma unroll
    for (int i = 0; i < K_; ++i) {
        float wm = cur;
#pragma unroll
        for (int off = 1; off < 64; off <<= 1) wm = fmaxf(wm, __shfl_xor(wm, off));
        T = wm;
        unsigned long long m = __ballot(cur == wm);
        int first = __ffsll(m) - 1;
        if (lane == first) cur = -INFINITY;
    }
    float kv[K_]; int ki[K_];
#pragma unroll
    for (int i = 0; i < K_; ++i) { kv[i] = -INFINITY; ki[i] = 0x7fffffff; }
#pragma unroll
    for (int g = 0; g < 32; ++g) {
        unsigned long long mk = __ballot(sv[g] >= T && sv[g] > kv[0]);
        while (mk) {
            int l = __ffsll(mk) - 1;
            mk &= mk - 1;
            float v = __shfl(sv[g], l);
            if (v > kv[0]) {
                kv[0] = v; ki[0] = g * 64 + l;
#pragma unroll
                for (int u = 0; u < K_ - 1; ++u)
                    if (kv[u] > kv[u + 1]) {
                        float tv = kv[u]; kv[u] = kv[u + 1]; kv[u + 1] = tv;
                        int tix = ki[u]; ki[u] = ki[u + 1]; ki[u + 1] = tix;
                    }
            }
        }
    }
    if (lane == 0) {
        int* op = idxout + ((size_t)b * N_ + n) * K_;
#pragma unroll
        for (int k = 0; k < K_; ++k) op[k] = ki[K_ - 1 - k];
    }
}

// ---------- scores GEMM via bf16 MFMA hi/lo 3-term, preconverted operands ----------
template <int C>
__global__ __launch_bounds__(256) void k_scores_mfma(const unsigned short* __restrict__ xhi,
                                                     const unsigned short* __restrict__ xlo,
                                                     const float* __restrict__ nrm,
                                                     float* __restrict__ S, int b0) {
    constexpr int RPC = C / 64;
    constexpr int NCH = 3 * RPC;
    constexpr int T = N_ / 64;
    __shared__ short AN[64 * 64];
    __shared__ short AM[64 * 64];
    const int bl = blockIdx.x;
    const int b = b0 + bl;
    int p = blockIdx.y;
    int r0 = 0, off = 0;
    while (off + (T - r0) <= p) { off += T - r0; ++r0; }
    const int ti = r0, tj = r0 + (p - off);
    const int n0 = ti * 64, m0 = tj * 64;
    const int t = threadIdx.x;
    const int lane = t & 63, w = t >> 6;
    const int colg = lane & 15, kg = lane >> 4;
    const size_t bbase = (size_t)b * N_;
    const float* nb = nrm + bbase;
    float* Sb = S + (size_t)bl * N_ * N_;

    f32x4 acc[4];
#pragma unroll
    for (int j = 0; j < 4; ++j) acc[j] = (f32x4){0.f, 0.f, 0.f, 0.f};

    for (int ch = 0; ch < NCH; ++ch) {
        const int region = ch / RPC;
        const int cc0 = (ch % RPC) * 64;
        const unsigned short* an_src = (region == 1) ? xlo : xhi;
        const unsigned short* am_src = (region == 2) ? xlo : xhi;
        __syncthreads();
#pragma unroll
        for (int e = 0; e < 2; ++e) {
            int idx = t + e * 256;
            int r = idx >> 3, k8 = idx & 7;
            uint4 vn = *(const uint4*)&an_src[(bbase + n0 + r) * C + cc0 + k8 * 8];
            uint4 vm = *(const uint4*)&am_src[(bbase + m0 + r) * C + cc0 + k8 * 8];
            int byte = (r * 128 + k8 * 16) ^ ((r & 7) << 4);
            *(uint4*)((char*)AN + byte) = vn;
            *(uint4*)((char*)AM + byte) = vm;
        }
        __syncthreads();
        const int arow = w * 16 + colg;
#pragma unroll
        for (int s = 0; s < 2; ++s) {
            int abyte = (arow * 128 + s * 64 + kg * 16) ^ ((arow & 7) << 4);
            bf16x8 af = *(const bf16x8*)((const char*)AN + abyte);
#pragma unroll
            for (int j = 0; j < 4; ++j) {
                int brow = j * 16 + colg;
                int bbyte = (brow * 128 + s * 64 + kg * 16) ^ ((brow & 7) << 4);
                bf16x8 bfr = *(const bf16x8*)((const char*)AM + bbyte);
                acc[j] = __builtin_amdgcn_mfma_f32_16x16x32_bf16(af, bfr, acc[j], 0, 0, 0);
            }
        }
    }
#pragma unroll
    for (int j = 0; j < 4; ++j) {
        float nm = nb[m0 + j * 16 + colg];
#pragma unroll
        for (int r = 0; r < 4; ++r) {
            int row = n0 + w * 16 + kg * 4 + r;
            Sb[(size_t)row * N_ + m0 + j * 16 + colg] = 2.f * acc[j][r] - nm;
        }
    }
    if (ti != tj) {
#pragma unroll
        for (int r = 0; r < 4; ++r) {
            int nrow = n0 + w * 16 + kg * 4 + r;
            float nn = nb[nrow];
#pragma unroll
            for (int j = 0; j < 4; ++j)
                Sb[(size_t)(m0 + j * 16 + colg) * N_ + nrow] = 2.f * acc[j][r] - nn;
        }
    }
}

// ---------- top-K scan: threshold-primed ballot-pop ----------
__global__ __launch_bounds__(256) void k_topk(const float* __restrict__ S,
                                              int* __restrict__ idxout, int b0) {
    const int bl = blockIdx.x, b = b0 + bl;
    const int wv = threadIdx.x >> 6, lane = threadIdx.x & 63;
    const int n = blockIdx.y * 4 + wv;
    const float* row = S + (size_t)bl * N_ * N_ + (size_t)n * N_;

    float sv[32];
#pragma unroll
    for (int g = 0; g < 32; ++g) sv[g] = __builtin_nontemporal_load(&row[g * 64 + lane]);

    float lm = sv[0];
#pragma unroll
    for (int g = 1; g < 32; ++g) lm = fmaxf(lm, sv[g]);

    float cur = lm, T = lm;
#pragma unroll
    for (int i = 0; i < K_; ++i) {
        float wm = cur;
#pragma unroll
        for (int off = 1; off < 64; off <<= 1) wm = fmaxf(wm, __shfl_xor(wm, off));
        T = wm;
        unsigned long long m = __ballot(cur == wm);
        int first = __ffsll(m) - 1;
        if (lane == first) cur = -INFINITY;
    }

    float kv[K_]; int ki[K_];
#pragma unroll
    for (int i = 0; i < K_; ++i) { kv[i] = -INFINITY; ki[i] = 0x7fffffff; }

#pragma unroll
    for (int g = 0; g < 32; ++g) {
        unsigned long long mk = __ballot(sv[g] >= T && sv[g] > kv[0]);
        while (mk) {
            int l = __ffsll(mk) - 1;
            mk &= mk - 1;
            float v = __shfl(sv[g], l);
            if (v > kv[0]) {
                kv[0] = v; ki[0] = g * 64 + l;
#pragma unroll
                for (int u = 0; u < K_ - 1; ++u)
                    if (kv[u] > kv[u + 1]) {
                        float tv = kv[u]; kv[u] = kv[u + 1]; kv[u + 1] = tv;
                        int tix = ki[u]; ki[u] = ki[u + 1]; ki[u + 1] = tix;
                    }
            }
        }
    }
    if (lane == 0) {
        int* op = idxout + ((size_t)b * N_ + n) * K_;
#pragma unroll
        for (int k = 0; k < K_; ++k) op[k] = ki[K_ - 1 - k];
    }
}

// ---------- center term ----------
template <int C, int O>
__global__ __launch_bounds__(256) void k_center(const float* __restrict__ xt, int LD, int OFF,
                                                const float* __restrict__ W,
                                                float* __restrict__ tbuf) {
    constexpr int KC = (C == 3) ? 4 : 32;
    __shared__ __align__(16) float XT[64][36];
    __shared__ __align__(16) float WDT[KC][68];
    const int b = blockIdx.x;
    const int n0 = blockIdx.y * 64;
    const int ob = blockIdx.z * 64;
    const int t = threadIdx.x;
    const int tn = t & 15, to = t >> 4;
    const float* xb = xt + ((size_t)b * N_) * LD + OFF;
    float4 acc[4];
#pragma unroll
    for (int i = 0; i < 4; ++i) acc[i] = make_float4(0, 0, 0, 0);
    for (int c0 = 0; c0 < C; c0 += KC) {
        __syncthreads();
        for (int e = t; e < 64 * KC; e += 256) {
            int r = e / KC, cc = e % KC;
            XT[r][cc] = (C == 3) ? ((cc < 3) ? xb[(size_t)(n0 + r) * LD + cc] : 0.f)
                                 : xb[(size_t)(n0 + r) * LD + c0 + cc];
        }
        for (int e = t; e < 64 * KC; e += 256) {
            int oo = e / KC, cc = e % KC;
            float wd, wc;
            if (C == 3) {
                wd = (cc < 3) ? W[(ob + oo) * 6 + cc] : 0.f;
                wc = (cc < 3) ? W[(ob + oo) * 6 + 3 + cc] : 0.f;
            } else {
                wd = W[(size_t)(ob + oo) * (2 * C) + c0 + cc];
                wc = W[(size_t)(ob + oo) * (2 * C) + C + c0 + cc];
            }
            WDT[cc][oo] = wc - wd;
        }
        __syncthreads();
#pragma unroll 4
        for (int cc = 0; cc < KC; ++cc) {
            float4 w4 = *(const float4*)&WDT[cc][to * 4];
#pragma unroll
            for (int i = 0; i < 4; ++i) {
                float a = XT[tn * 4 + i][cc];
                acc[i].x += a * w4.x; acc[i].y += a * w4.y;
                acc[i].z += a * w4.z; acc[i].w += a * w4.w;
            }
        }
    }
#pragma unroll
    for (int i = 0; i < 4; ++i)
        *(float4*)&tbuf[((size_t)b * N_ + n0 + tn * 4 + i) * O + ob + to * 4] = acc[i];
}

// ---------- fp32 edge conv (block 1 only, C=3) ----------
template <int C, int O>
__global__ __launch_bounds__(256) void k_conv(const float* __restrict__ xt, int LDI, int OFFI,
                                              const int* __restrict__ idx,
                                              const float* __restrict__ W,
                                              const float* __restrict__ tbuf,
                                              float* __restrict__ hout, int OFFO) {
    constexpr int KC = (C == 3) ? 4 : 32;
    __shared__ __align__(16) float A[160][36];
    __shared__ __align__(16) float WT[KC][68];
    __shared__ int nb_s[160];
    const int b = blockIdx.x;
    const int n0 = blockIdx.y * 16;
    const int t = threadIdx.x;
    const int p = t >> 4, og = t & 15;
    if (t < 160) nb_s[t] = idx[((size_t)b * N_ + n0 + t / K_) * K_ + (t % K_)];
    const float* xb = xt + ((size_t)b * N_) * LDI + OFFI;

    for (int ob = 0; ob < O; ob += 64) {
        float4 acc[K_];
#pragma unroll
        for (int j = 0; j < K_; ++j) acc[j] = make_float4(0, 0, 0, 0);
        for (int c0 = 0; c0 < C; c0 += KC) {
            __syncthreads();
            if (C == 3) {
                for (int e = t; e < 160 * 4; e += 256) {
                    int r = e / 4, cc = e % 4;
                    A[r][cc] = (cc < 3) ? xb[(size_t)nb_s[r] * LDI + cc] : 0.f;
                }
            } else {
                for (int e = t; e < 160 * 8; e += 256) {
                    int r = e / 8, c4 = e % 8;
                    *(float4*)&A[r][c4 * 4] =
                        *(const float4*)&xb[(size_t)nb_s[r] * LDI + c0 + c4 * 4];
                }
            }
            for (int e = t; e < 64 * KC; e += 256) {
                int oo = e / KC, cc = e % KC;
                float w;
                if (C == 3) w = (cc < 3) ? W[(ob + oo) * 6 + cc] : 0.f;
                else        w = W[(size_t)(ob + oo) * (2 * C) + c0 + cc];
                WT[cc][oo] = w;
            }
            __syncthreads();
#pragma unroll 4
            for (int cc = 0; cc < KC; ++cc) {
                float4 w4 = *(const float4*)&WT[cc][og * 4];
#pragma unroll
                for (int j = 0; j < K_; ++j) {
                    float a = A[p * K_ + j][cc];
                    acc[j].x += a * w4.x; acc[j].y += a * w4.y;
                    acc[j].z += a * w4.z; acc[j].w += a * w4.w;
                }
            }
        }
        float4 tv = *(const float4*)&tbuf[((size_t)b * N_ + n0 + p) * O + ob + og * 4];
        float4 mx = acc[0];
#pragma unroll
        for (int j = 1; j < K_; ++j) {
            mx.x = fmaxf(mx.x, acc[j].x); mx.y = fmaxf(mx.y, acc[j].y);
            mx.z = fmaxf(mx.z, acc[j].z); mx.w = fmaxf(mx.w, acc[j].w);
        }
        float4 r;
        r.x = lrelu(mx.x + tv.x); r.y = lrelu(mx.y + tv.y);
        r.z = lrelu(mx.z + tv.z); r.w = lrelu(mx.w + tv.w);
        *(float4*)&hout[((size_t)b * N_ + n0 + p) * 512 + OFFO + ob + og * 4] = r;
    }
}

// ---------- blocks 2-3 edge conv via hi/lo MFMA ----------
template <int O>
__global__ __launch_bounds__(256) void k_conv23_mfma(const float* __restrict__ hcat, int OFFI,
                                                     const int* __restrict__ idx,
                                                     const short* __restrict__ Wh,
                                                     const short* __restrict__ Wl,
                                                     const float* __restrict__ tbuf,
                                                     float* __restrict__ hout, int OFFO) {
    constexpr int CT = O / 64;
    __shared__ short Ah[160 * 64];
    __shared__ short Al[160 * 64];
    __shared__ int nb_s[160];
    const int b = blockIdx.x;
    const int n0 = blockIdx.y * 16;
    const int t = threadIdx.x;
    const int lane = t & 63, wv = t >> 6;
    const int colg = lane & 15, kg = lane >> 4;
    if (t < 160) nb_s[t] = idx[((size_t)b * N_ + n0 + t / K_) * K_ + (t % K_)];
    __syncthreads();
    for (int e = t; e < 160 * 16; e += 256) {
        int r = e >> 4, q = e & 15;
        const float4 v = *(const float4*)&hcat[((size_t)b * N_ + nb_s[r]) * 512 + OFFI + q * 4];
        float a4[4] = {v.x, v.y, v.z, v.w};
        short sh[4], sl[4];
#pragma unroll
        for (int c2 = 0; c2 < 4; ++c2) {
            sh[c2] = f2bf(a4[c2]);
            sl[c2] = f2bf(a4[c2] - bf2f(sh[c2]));
        }
        int byte = r * 128 + ((q * 8) ^ (((r / K_) & 7) << 4));
        *(short4*)((char*)Ah + byte) = make_short4(sh[0], sh[1], sh[2], sh[3]);
        *(short4*)((char*)Al + byte) = make_short4(sl[0], sl[1], sl[2], sl[3]);
    }
    bf16x8 bh[CT][2], blo[CT][2];
    const int obase = wv * (O / 4);
#pragma unroll
    for (int ct = 0; ct < CT; ++ct)
#pragma unroll
        for (int ks = 0; ks < 2; ++ks) {
            int o = obase + ct * 16 + colg;
            bh[ct][ks]  = *(const bf16x8*)&Wh[(size_t)o * 64 + ks * 32 + kg * 8];
            blo[ct][ks] = *(const bf16x8*)&Wl[(size_t)o * 64 + ks * 32 + kg * 8];
        }
    __syncthreads();

    f32x4 macc[CT];
#pragma unroll
    for (int ct = 0; ct < CT; ++ct)
        macc[ct] = (f32x4){-INFINITY, -INFINITY, -INFINITY, -INFINITY};

    const int aswz = (colg & 7) << 4;
#pragma unroll
    for (int j = 0; j < K_; ++j) {
        const int arow = colg * K_ + j;
        bf16x8 afh[2], afl[2];
#pragma unroll
        for (int ks = 0; ks < 2; ++ks) {
            int byte = arow * 128 + ((ks * 64 + kg * 16) ^ aswz);
            afh[ks] = *(const bf16x8*)((const char*)Ah + byte);
            afl[ks] = *(const bf16x8*)((const char*)Al + byte);
        }
        f32x4 acc[CT];
#pragma unroll
        for (int ct = 0; ct < CT; ++ct) acc[ct] = (f32x4){0.f, 0.f, 0.f, 0.f};
#pragma unroll
        for (int ks = 0; ks < 2; ++ks)
#pragma unroll
            for (int ct = 0; ct < CT; ++ct)
                acc[ct] = __builtin_amdgcn_mfma_f32_16x16x32_bf16(afh[ks], bh[ct][ks], acc[ct], 0, 0, 0);
#pragma unroll
        for (int ks = 0; ks < 2; ++ks)
#pragma unroll
            for (int ct = 0; ct < CT; ++ct)
                acc[ct] = __builtin_amdgcn_mfma_f32_16x16x32_bf16(afl[ks], bh[ct][ks], acc[ct], 0, 0, 0);
#pragma unroll
        for (int ks = 0; ks < 2; ++ks)
#pragma unroll
            for (int ct = 0; ct < CT; ++ct)
                acc[ct] = __builtin_amdgcn_mfma_f32_16x16x32_bf16(afh[ks], blo[ct][ks], acc[ct], 0, 0, 0);
#pragma unroll
        for (int ct = 0; ct < CT; ++ct) {
            macc[ct].x = fmaxf(macc[ct].x, acc[ct].x);
            macc[ct].y = fmaxf(macc[ct].y, acc[ct].y);
            macc[ct].z = fmaxf(macc[ct].z, acc[ct].z);
            macc[ct].w = fmaxf(macc[ct].w, acc[ct].w);
        }
    }
#pragma unroll
    for (int ct = 0; ct < CT; ++ct)
#pragma unroll
        for (int r = 0; r < 4; ++r) {
            int p = kg * 4 + r;
            int o = obase + ct * 16 + colg;
            float v = macc[ct][r] + tbuf[((size_t)b * N_ + n0 + p) * O + o];
            hout[((size_t)b * N_ + n0 + p) * 512 + OFFO + o] = lrelu(v);
        }
}

// ---------- block-4 edge conv via bf16 MFMA ----------
__global__ __launch_bounds__(256) void k_conv4_mfma(const float* __restrict__ hcat,
                                                    const int* __restrict__ idx,
                                                    const short* __restrict__ Wb,
                                                    const float* __restrict__ tbuf,
                                                    float* __restrict__ hout) {
    __shared__ short Ab[160 * 128];
    __shared__ int nb_s[160];
    const int b = blockIdx.x;
    const int n0 = blockIdx.y * 16;
    const int t = threadIdx.x;
    const int lane = t & 63, wv = t >> 6;
    const int colg = lane & 15, kg = lane >> 4;
    if (t < 160) nb_s[t] = idx[((size_t)b * N_ + n0 + t / K_) * K_ + (t % K_)];
    __syncthreads();
    for (int e = t; e < 160 * 32; e += 256) {
        int r = e >> 5, q = e & 31;
        const float4 v = *(const float4*)&hcat[((size_t)b * N_ + nb_s[r]) * 512 + 128 + q * 4];
        short4 s4 = { f2bf(v.x), f2bf(v.y), f2bf(v.z), f2bf(v.w) };
        int byte = r * 256 + ((q * 8) ^ (((r / K_) & 7) << 4));
        *(short4*)((char*)Ab + byte) = s4;
    }
    bf16x8 bf[4][4];
    const int ob = wv * 64;
#pragma unroll
    for (int nt = 0; nt < 4; ++nt)
#pragma unroll
        for (int ks = 0; ks < 4; ++ks)
            bf[nt][ks] = *(const bf16x8*)&Wb[(size_t)(ob + nt * 16 + colg) * 128 + ks * 32 + kg * 8];
    __syncthreads();

    f32x4 macc[4];
#pragma unroll
    for (int nt = 0; nt < 4; ++nt)
        macc[nt] = (f32x4){-INFINITY, -INFINITY, -INFINITY, -INFINITY};

    const int arow = colg * K_;
    const int aswz = (colg & 7) << 4;
#pragma unroll
    for (int j = 0; j < K_; ++j) {
        f32x4 acc[4];
#pragma unroll
        for (int nt = 0; nt < 4; ++nt) acc[nt] = (f32x4){0.f, 0.f, 0.f, 0.f};
#pragma unroll
        for (int ks = 0; ks < 4; ++ks) {
            int byte = (arow + j) * 256 + (((ks * 32 + kg * 8) * 2) ^ aswz);
            bf16x8 af = *(const bf16x8*)((const char*)Ab + byte);
#pragma unroll
            for (int nt = 0; nt < 4; ++nt)
                acc[nt] = __builtin_amdgcn_mfma_f32_16x16x32_bf16(af, bf[nt][ks], acc[nt], 0, 0, 0);
        }
#pragma unroll
        for (int nt = 0; nt < 4; ++nt) {
            macc[nt].x = fmaxf(macc[nt].x, acc[nt].x);
            macc[nt].y = fmaxf(macc[nt].y, acc[nt].y);
            macc[nt].z = fmaxf(macc[nt].z, acc[nt].z);
            macc[nt].w = fmaxf(macc[nt].w, acc[nt].w);
        }
    }
#pragma unroll
    for (int nt = 0; nt < 4; ++nt)
#pragma unroll
        for (int r = 0; r < 4; ++r) {
            int p = kg * 4 + r;
            int o = ob + nt * 16 + colg;
            float v = macc[nt][r] + tbuf[((size_t)b * N_ + n0 + p) * 256 + o];
            hout[((size_t)b * N_ + n0 + p) * 512 + 256 + o] = lrelu(v);
        }
}

// ---------- final conv W5 via bf16 MFMA + fused lrelu/max/sum reduce ----------
__global__ __launch_bounds__(256) void k_final_mfma(const float* __restrict__ hcat,
                                                    const short* __restrict__ W5b,
                                                    float* __restrict__ pmax,
                                                    float* __restrict__ psum) {
    __shared__ short Ab[64 * 128];
    const int b = blockIdx.x, nc = blockIdx.y, obk = blockIdx.z;
    const int n0 = nc * 64, ob = obk * 64;
    const int t = threadIdx.x, lane = t & 63, wv = t >> 6;
    const int colg = lane & 15, kg = lane >> 4;
    const int o = ob + wv * 16 + colg;

    f32x4 acc[4];
#pragma unroll
    for (int mt = 0; mt < 4; ++mt) acc[mt] = (f32x4){0.f, 0.f, 0.f, 0.f};

    for (int kc = 0; kc < 4; ++kc) {
        __syncthreads();
        for (int e = t; e < 64 * 32; e += 256) {
            int r = e >> 5, q = e & 31;
            const float4 v = *(const float4*)&hcat[((size_t)b * N_ + n0 + r) * 512 + kc * 128 + q * 4];
            short4 s4 = { f2bf(v.x), f2bf(v.y), f2bf(v.z), f2bf(v.w) };
            int byte = r * 256 + ((q * 8) ^ ((r & 7) << 4));
            *(short4*)((char*)Ab + byte) = s4;
        }
        __syncthreads();
#pragma unroll
        for (int ks = 0; ks < 4; ++ks) {
            bf16x8 bfrag = *(const bf16x8*)&W5b[(size_t)o * 512 + kc * 128 + ks * 32 + kg * 8];
#pragma unroll
            for (int mt = 0; mt < 4; ++mt) {
                int row = mt * 16 + colg;
                int byte = row * 256 + (((ks * 32 + kg * 8) * 2) ^ ((row & 7) << 4));
                bf16x8 af = *(const bf16x8*)((const char*)Ab + byte);
                acc[mt] = __builtin_amdgcn_mfma_f32_16x16x32_bf16(af, bfrag, acc[mt], 0, 0, 0);
            }
        }
    }
    float mx = -INFINITY, sm = 0.f;
#pragma unroll
    for (int mt = 0; mt < 4; ++mt)
#pragma unroll
        for (int r = 0; r < 4; ++r) {
            float v = lrelu(acc[mt][r]);
            mx = fmaxf(mx, v); sm += v;
        }
    mx = fmaxf(mx, __shfl_xor(mx, 16)); sm += __shfl_xor(sm, 16);
    mx = fmaxf(mx, __shfl_xor(mx, 32)); sm += __shfl_xor(sm, 32);
    if (lane < 16) {
        pmax[((size_t)b * 512 + ob + wv * 16 + lane) * 32 + nc] = mx;
        psum[((size_t)b * 512 + ob + wv * 16 + lane) * 32 + nc] = sm;
    }
}

// ---------- pool combine ----------
__global__ __launch_bounds__(256) void k_pool(const float* __restrict__ pmax,
                                              const float* __restrict__ psum,
                                              float* __restrict__ f) {
    int i = blockIdx.x * 256 + threadIdx.x;
    if (i >= B_ * 512) return;
    int b = i >> 9, o = i & 511;
    const float* pm = pmax + (size_t)i * 32;
    const float* ps = psum + (size_t)i * 32;
    float mm = -INFINITY, ss = 0.f;
#pragma unroll
    for (int q = 0; q < 32; ++q) { mm = fmaxf(mm, pm[q]); ss += ps[q]; }
    f[(size_t)b * 1024 + o] = mm;
    f[(size_t)b * 1024 + 512 + o] = ss * (1.0f / 2048.0f);
}

// ---------- FC1 ----------
__global__ __launch_bounds__(256) void k_fc1(const float* __restrict__ f,
                                             const float* __restrict__ L1,
                                             float* __restrict__ f1) {
    __shared__ float fs[8][1024];
    const int t = threadIdx.x, lane = t & 63, w = t >> 6;
    for (int e = t; e < 2048; e += 256)
        *(float4*)&fs[0][e * 4] = *(const float4*)&f[e * 4];
    __syncthreads();
    const int o = blockIdx.x * 4 + w;
    float acc[8];
#pragma unroll
    for (int b = 0; b < 8; ++b) acc[b] = 0.f;
    const float* Lrow = L1 + (size_t)o * 1024;
#pragma unroll
    for (int e = 0; e < 16; ++e) {
        float wv = Lrow[e * 64 + lane];
#pragma unroll
        for (int b = 0; b < 8; ++b) acc[b] += wv * fs[b][e * 64 + lane];
    }
#pragma unroll
    for (int off = 32; off; off >>= 1)
#pragma unroll
        for (int b = 0; b < 8; ++b) acc[b] += __shfl_xor(acc[b], off);
#pragma unroll
    for (int b = 0; b < 8; ++b)
        if (lane == b) f1[(size_t)b * 512 + o] = lrelu(acc[b]);
}

// ---------- FC2 ----------
__global__ __launch_bounds__(256) void k_fc2(const float* __restrict__ f1,
                                             const float* __restrict__ L2,
                                             const float* __restrict__ b2,
                                             float* __restrict__ out) {
    __shared__ float fs[8][512];
    const int t = threadIdx.x, lane = t & 63, w = t >> 6;
    for (int e = t; e < 1024; e += 256)
        *(float4*)&fs[0][e * 4] = *(const float4*)&f1[e * 4];
    __syncthreads();
    const int o = blockIdx.x * 4 + w;
    float acc[8];
#pragma unroll
    for (int b = 0; b < 8; ++b) acc[b] = 0.f;
    const float* Lrow = L2 + (size_t)o * 512;
#pragma unroll
    for (int e = 0; e < 8; ++e) {
        float wv = Lrow[e * 64 + lane];
#pragma unroll
        for (int b = 0; b < 8; ++b) acc[b] += wv * fs[b][e * 64 + lane];
    }
#pragma unroll
    for (int off = 32; off; off >>= 1)
#pragma unroll
        for (int b = 0; b < 8; ++b) acc[b] += __shfl_xor(acc[b], off);
    float bb = b2[o];
#pragma unroll
    for (int b = 0; b < 8; ++b)
        if (lane == b) out[(size_t)b * 256 + o] = lrelu(acc[b] + bb);
}

extern "C" void kernel_launch(void* const* d_in, const int* in_sizes, int n_in,
                              void* d_out, int out_size, void* d_ws, size_t ws_size,
                              hipStream_t stream) {
    (void)in_sizes; (void)n_in; (void)out_size;
    const float* x  = (const float*)d_in[0];
    const float* W1 = (const float*)d_in[1];
    const float* W2 = (const float*)d_in[2];
    const float* W3 = (const float*)d_in[3];
    const float* W4 = (const float*)d_in[4];
    const float* W5 = (const float*)d_in[5];
    const float* L1 = (const float*)d_in[6];
    const float* L2 = (const float*)d_in[7];
    const float* b2 = (const float*)d_in[8];
    float* out = (float*)d_out;

    // workspace layout (float units)
    float* ws   = (float*)d_ws;
    float* xt   = ws;                                    // 49152
    float* nrm  = xt + (size_t)B_ * N_ * 3;              // 16384
    int*   idxb = (int*)(nrm + (size_t)B_ * N_);         // 163840
    float* tb   = (float*)(idxb + (size_t)B_ * N_ * K_); // 4194304
    float* hcat = tb + (size_t)B_ * N_ * 256;            // 8388608
    float* pmax = hcat + (size_t)B_ * N_ * 512;          // 131072
    float* psum = pmax + (size_t)B_ * 512 * 32;          // 131072
    short* wb4  = (short*)(psum + (size_t)B_ * 512 * 32);// 16384 floats
    short* w5b  = wb4 + 256 * 128;                       // 131072 floats
    short* w2h  = w5b + 512 * 512;                       // 64*64
    short* w2l  = w2h + 64 * 64;
    short* w3h  = w2l + 64 * 64;                         // 128*64
    short* w3l  = w3h + 128 * 64;
    float* fbuf = (float*)(w3l + 128 * 64);              // 8192
    float* f1b  = fbuf + 8192;                           // 4096
    unsigned short* xh = (unsigned short*)(f1b + 4096);  // B*N*128 shorts
    unsigned short* xl = xh + (size_t)B_ * N_ * 128;
    float* scor = (float*)(xl + (size_t)B_ * N_ * 128);  // CH * N*N fp32

    const size_t base_f = 49152 + 16384 + 163840 + 4194304 + 8388608 +
                          131072 + 131072 + 16384 + 131072 + 12288 + 8192 + 4096 +
                          2097152;
    const size_t nsq = (size_t)N_ * N_;
    size_t avail = (ws_size / 4 > base_f) ? (ws_size / 4 - base_f) : 0;
    int CH = 1;
    if (avail >= 8 * nsq) CH = 8;
    else if (avail >= 4 * nsq) CH = 4;
    else if (avail >= 2 * nsq) CH = 2;

    constexpr int TP = (N_ / 64) * (N_ / 64 + 1) / 2;  // 528

    dim3 blk(256);
    k_transpose<<<dim3((B_ * N_ + 255) / 256), blk, 0, stream>>>(x, xt);
    k_cvt<<<dim3((256 * 128 + 512 * 512 + 255) / 256), blk, 0, stream>>>(W4, W5, wb4, w5b);
    k_cvt2<<<dim3((64 * 64 + 128 * 64 + 255) / 256), blk, 0, stream>>>(W2, W3, w2h, w2l, w3h, w3l);

    // block 1: fused kNN (round-19 proven version)
    k_knn3<<<dim3(B_, N_ / 4), blk, 0, stream>>>(x, idxb);
    k_center<3, 64><<<dim3(B_, N_ / 64, 1), blk, 0, stream>>>(xt, 3, 0, W1, tb);
    k_conv<3, 64><<<dim3(B_, N_ / 16), blk, 0, stream>>>(xt, 3, 0, idxb, W1, tb, hcat, 0);

    // block 2
    k_prep<64><<<dim3(B_ * N_ / 4), blk, 0, stream>>>(hcat, 0, xh, xl, nrm);
    for (int b0 = 0; b0 < B_; b0 += CH) {
        k_scores_mfma<64><<<dim3(CH, TP), blk, 0, stream>>>(xh, xl, nrm, scor, b0);
        k_topk<<<dim3(CH, N_ / 4), blk, 0, stream>>>(scor, idxb, b0);
    }
    k_center<64, 64><<<dim3(B_, N_ / 64, 1), blk, 0, stream>>>(hcat, 512, 0, W2, tb);
    k_conv23_mfma<64><<<dim3(B_, N_ / 16), blk, 0, stream>>>(hcat, 0, idxb, w2h, w2l, tb, hcat, 64);

    // block 3
    k_prep<64><<<dim3(B_ * N_ / 4), blk, 0, stream>>>(hcat, 64, xh, xl, nrm);
    for (int b0 = 0; b0 < B_; b0 += CH) {
        k_scores_mfma<64><<<dim3(CH, TP), blk, 0, stream>>>(xh, xl, nrm, scor, b0);
        k_topk<<<dim3(CH, N_ / 4), blk, 0, stream>>>(scor, idxb, b0);
    }
    k_center<64, 128><<<dim3(B_, N_ / 64, 2), blk, 0, stream>>>(hcat, 512, 64, W3, tb);
    k_conv23_mfma<128><<<dim3(B_, N_ / 16), blk, 0, stream>>>(hcat, 64, idxb, w3h, w3l, tb, hcat, 128);

    // block 4 (MFMA conv)
    k_prep<128><<<dim3(B_ * N_ / 4), blk, 0, stream>>>(hcat, 128, xh, xl, nrm);
    for (int b0 = 0; b0 < B_; b0 += CH) {
        k_scores_mfma<128><<<dim3(CH, TP), blk, 0, stream>>>(xh, xl, nrm, scor, b0);
        k_topk<<<dim3(CH, N_ / 4), blk, 0, stream>>>(scor, idxb, b0);
    }
    k_center<128, 256><<<dim3(B_, N_ / 64, 4), blk, 0, stream>>>(hcat, 512, 128, W4, tb);
    k_conv4_mfma<<<dim3(B_, N_ / 16), blk, 0, stream>>>(hcat, idxb, wb4, tb, hcat);

    // final conv + parallelized head
    k_final_mfma<<<dim3(B_, 32, 8), blk, 0, stream>>>(hcat, w5b, pmax, psum);
    k_pool<<<dim3(B_ * 512 / 256), blk, 0, stream>>>(pmax, psum, fbuf);
    k_fc1<<<dim3(128), blk, 0, stream>>>(fbuf, L1, f1b);
    k_fc2<<<dim3(64), blk, 0, stream>>>(f1b, L2, b2, out);
}